// Round 1
// baseline (55.563 us; speedup 1.0000x reference)
//
#include <hip/hip_runtime.h>

#define IMG_H 256
#define IMG_W 256
#define STRIPS 8
#define ROWS (IMG_H / STRIPS)   // 32 output rows per block

// Block: 256 threads, one per column. Processes ROWS output rows of one image.
// Separable 7x7 Gaussian: horizontal pass via LDS row buffer (double-buffered),
// vertical pass via 7-deep register shift window (static indexing only).
__global__ __launch_bounds__(256) void ssim_main(
    const float* __restrict__ pred,
    const float* __restrict__ targ,
    const float* __restrict__ window,
    float* __restrict__ acc)
{
    __shared__ float sp[2][IMG_W + 6];
    __shared__ float st[2][IMG_W + 6];
    __shared__ float wsum[4];

    const int x   = threadIdx.x;            // column 0..255
    const int blk = blockIdx.x;
    const int n   = blk / STRIPS;           // image index
    const int s   = blk % STRIPS;           // strip index
    const int r0  = s * ROWS;               // first output row of this strip

    // Recover exact 1D gaussian from 2D window: w2d[3][j] = g[3]*g[j],
    // sum_j w2d[3][j] = g[3]  =>  g[j] = w[21+j] / sum.
    float g[7];
    {
        float sum = 0.f;
#pragma unroll
        for (int j = 0; j < 7; ++j) { g[j] = window[21 + j]; sum += g[j]; }
        float inv = 1.0f / sum;
#pragma unroll
        for (int j = 0; j < 7; ++j) g[j] *= inv;
    }

    // Zero the x-halo (columns -3..-1 and 256..258) once; they never change.
    if (x < 3) {
        sp[0][x] = 0.f; sp[1][x] = 0.f;
        st[0][x] = 0.f; st[1][x] = 0.f;
        sp[0][IMG_W + 3 + x] = 0.f; sp[1][IMG_W + 3 + x] = 0.f;
        st[0][IMG_W + 3 + x] = 0.f; st[1][IMG_W + 3 + x] = 0.f;
    }
    __syncthreads();

    const float* pn = pred + (size_t)n * IMG_H * IMG_W;
    const float* tn = targ + (size_t)n * IMG_H * IMG_W;

    // 7-deep shift windows of horizontally-convolved rows.
    float hp[7], ht[7], hpp[7], htt[7], hpt[7];

    const float C1 = 1e-4f;   // 0.01^2
    const float C2 = 9e-4f;   // 0.03^2

    float local = 0.f;
    int buf = 0;

    // Input rows j = r0-3 .. r0+ROWS+2  (ROWS+6 iterations)
    for (int jj = 0; jj < ROWS + 6; ++jj) {
        const int j = r0 - 3 + jj;
        const bool inr = (j >= 0) && (j < IMG_H);

        float vp = 0.f, vt = 0.f;
        if (inr) {
            vp = pn[j * IMG_W + x];
            vt = tn[j * IMG_W + x];
        }
        sp[buf][3 + x] = vp;
        st[buf][3 + x] = vt;
        __syncthreads();   // one sync per row suffices (double-buffered)

        float a0 = 0.f, a1 = 0.f, a2 = 0.f, a3 = 0.f, a4 = 0.f;
        if (inr) {
#pragma unroll
            for (int d = 0; d < 7; ++d) {
                float p = sp[buf][x + d];       // column x + d - 3 (halo = 0)
                float t = st[buf][x + d];
                float w = g[d];
                float wp = w * p;
                float wt = w * t;
                a0 += wp;
                a1 += wt;
                a2 = fmaf(wp, p, a2);
                a3 = fmaf(wt, t, a3);
                a4 = fmaf(wp, t, a4);
            }
        }

        // shift the vertical windows (static indices)
#pragma unroll
        for (int k = 0; k < 6; ++k) {
            hp[k] = hp[k + 1]; ht[k] = ht[k + 1];
            hpp[k] = hpp[k + 1]; htt[k] = htt[k + 1]; hpt[k] = hpt[k + 1];
        }
        hp[6] = a0; ht[6] = a1; hpp[6] = a2; htt[6] = a3; hpt[6] = a4;

        if (jj >= 6) {
            // output row r = j - 3; hp[0..6] = h rows r-3..r+3
            float mu1 = 0.f, mu2 = 0.f, spp = 0.f, stt = 0.f, spt = 0.f;
#pragma unroll
            for (int k = 0; k < 7; ++k) {
                float w = g[k];
                mu1 = fmaf(w, hp[k], mu1);
                mu2 = fmaf(w, ht[k], mu2);
                spp = fmaf(w, hpp[k], spp);
                stt = fmaf(w, htt[k], stt);
                spt = fmaf(w, hpt[k], spt);
            }
            float mu1s = mu1 * mu1;
            float mu2s = mu2 * mu2;
            float mu12 = mu1 * mu2;
            float s1  = spp - mu1s;
            float s2  = stt - mu2s;
            float s12 = spt - mu12;
            float num = (2.f * mu12 + C1) * (2.f * s12 + C2);
            float den = (mu1s + mu2s + C1) * (s1 + s2 + C2);
            local += num / den;
        }
        buf ^= 1;
    }

    // block reduction: wave shuffle, then cross-wave via LDS, one atomic/block
#pragma unroll
    for (int off = 32; off > 0; off >>= 1)
        local += __shfl_down(local, off, 64);
    const int lane = threadIdx.x & 63;
    const int wid  = threadIdx.x >> 6;
    if (lane == 0) wsum[wid] = local;
    __syncthreads();
    if (threadIdx.x == 0) {
        float b = wsum[0] + wsum[1] + wsum[2] + wsum[3];
        atomicAdd(acc, b);
    }
}

__global__ void ssim_final(const float* __restrict__ acc, float* __restrict__ out)
{
    out[0] = 1.0f - acc[0] * (1.0f / (128.0f * 256.0f * 256.0f));
}

extern "C" void kernel_launch(void* const* d_in, const int* in_sizes, int n_in,
                              void* d_out, int out_size, void* d_ws, size_t ws_size,
                              hipStream_t stream)
{
    const float* pred   = (const float*)d_in[0];
    const float* targ   = (const float*)d_in[1];
    const float* window = (const float*)d_in[2];
    float* out = (float*)d_out;
    float* acc = (float*)d_ws;

    const int n_img = in_sizes[0] / (IMG_H * IMG_W);   // 128

    // d_ws is not re-poisoned between replays: zero the accumulator each call.
    hipMemsetAsync(acc, 0, sizeof(float), stream);

    ssim_main<<<n_img * STRIPS, 256, 0, stream>>>(pred, targ, window, acc);
    ssim_final<<<1, 1, 0, stream>>>(acc, out);
    (void)n_in; (void)out_size; (void)ws_size;
}